// Round 4
// baseline (520.175 us; speedup 1.0000x reference)
//
#include <hip/hip_runtime.h>

// EnsembleLayer: y[b, n*32+c] = sum_c' M[n][c][c'] * x[b, clusters[n][c']] + bias[n][c]
// where M[n] = dec_w[n] @ enc_w[n]  (fused encoder+decoder, one pass)
//
// B=131072, F=512, NC=16, CS=32, NH=16.
//
// Round-3 post-mortem: double-buffer pipeline was neutral (170->167us). LDS pipe
// is ~60% busy (16 lanes/cluster each privately re-read the same 128B row:
// 1024 ds_read_b128/thread = ~82us/CU). This version replaces the LDS broadcast
// with a DPP lane-rotation broadcast (VALU pipe):
//   - each lane reads only ITS 8B of the cluster row (ds_read_b64) -> 8x fewer LDS reads
//   - x-pairs rotate around the 16-lane DPP row via v_mov_dpp row_ror:1
//   - M coefficients stored per-lane in rotation order (static reg indices)
//   - rotation direction probed at runtime (no DPP direction-convention risk)
// New expected balance: HBM 64us (wall) / VALU ~45us / LDS ~25us.

#define B_ROWS   131072
#define F        512
#define NC       16
#define CS       32
#define NH       16
#define NBLOCKS  1024
#define RPB      128   // rows per block
#define RPI      4     // rows per iteration
#define NITER    (RPB / RPI)

__device__ __forceinline__ float ror1_f(float v) {
    // rotate within each 16-lane DPP row by one lane (VALU pipe, no LDS)
    return __int_as_float(__builtin_amdgcn_update_dpp(
        0, __float_as_int(v), 0x121 /*row_ror:1*/, 0xF, 0xF, false));
}

__global__ __launch_bounds__(256, 4)
void ensemble_kernel(const float* __restrict__ x,
                     const int*   __restrict__ clusters,
                     const float* __restrict__ enc_w,
                     const float* __restrict__ enc_b,
                     const float* __restrict__ dec_w,
                     const float* __restrict__ dec_b,
                     float*       __restrict__ out) {
    // xi tile (double-buffered), PLAIN layout: value xi[n*32+c] at slot n*32+c.
    // b64 reads are inherently 4-way bank-aliased (512B over 32 banks) -> cheap.
    __shared__ float s_xi[2][RPI][F];   // 16 KB
    __shared__ int   s_tgt[F];          // s_tgt[src_col] = xi slot (inverse perm)

    const int t = threadIdx.x;

    // ---- build inverse-permutation target table (once per block) ----
    for (int j = t; j < F; j += 256) s_tgt[clusters[j]] = j;
    __syncthreads();

    // cache my 4 scatter targets (I always load the same 4 source columns)
    const int cbase = (t & 127) << 2;
    const int tgt0 = s_tgt[cbase + 0];
    const int tgt1 = s_tgt[cbase + 1];
    const int tgt2 = s_tgt[cbase + 2];
    const int tgt3 = s_tgt[cbase + 3];

    const int n  = t >> 4;                     // my cluster (16 lanes each = DPP row)
    const int lc = t & 15;                     // lane within cluster
    const int rhalf = t >> 7;                  // which row of a 2-row pass I load
    const int row_block = blockIdx.x * RPB;

    const float* xp = x + (size_t)(row_block + rhalf) * F + cbase;
    const int xioff = (n << 5) + (lc << 1);    // my 8B of the xi row
    float* op = out + (size_t)row_block * F + xioff;

    // ---- issue the first tile's loads NOW; latency hides under M-setup ----
    float4 v[2];
    v[0] = *(const float4*)(xp);
    v[1] = *(const float4*)(xp + 2 * F);
    xp += RPI * F;

    // ---- probe DPP rotation direction: after one ror1, which orig lane do I hold?
    const int sl = __builtin_amdgcn_update_dpp(0, lc, 0x121, 0xF, 0xF, false);
    const int d  = (((sl - lc) & 15) == 1) ? 1 : 15;   // orig-lane step per rotation (mod 16)

    // ---- dec_w rows for my 2 output columns (c = 2lc, 2lc+1) ----
    float dw0[NH], dw1[NH];
    {
        const float4* p0 = (const float4*)(dec_w + (size_t)(n * CS + (lc << 1))     * NH);
        const float4* p1 = (const float4*)(dec_w + (size_t)(n * CS + (lc << 1) + 1) * NH);
        #pragma unroll
        for (int q = 0; q < 4; ++q) {
            float4 a = p0[q];
            dw0[4*q+0] = a.x; dw0[4*q+1] = a.y; dw0[4*q+2] = a.z; dw0[4*q+3] = a.w;
            float4 b = p1[q];
            dw1[4*q+0] = b.x; dw1[4*q+1] = b.y; dw1[4*q+2] = b.z; dw1[4*q+3] = b.w;
        }
    }

    // fused bias: b = dec_b + dec_w @ enc_b
    float b0 = dec_b[n * CS + (lc << 1)];
    float b1 = dec_b[n * CS + (lc << 1) + 1];
    #pragma unroll
    for (int h = 0; h < NH; ++h) {
        const float eb = enc_b[n * NH + h];
        b0 += dw0[h] * eb;
        b1 += dw1[h] * eb;
    }

    // ---- M coefficients in ROTATION order: at step s my x regs hold
    // xi[n][cp], xi[n][cp+1] with cp = 2*((lc + d*s) & 15). Store
    // mA*(for output 2lc) / mB*(for 2lc+1) so step s uses reg index s (static).
    float mA0[16], mA1[16], mB0[16], mB1[16];
    #pragma unroll
    for (int s = 0; s < 16; ++s) {
        const int cp = ((lc + d * s) & 15) << 1;
        const float* ep = enc_w + (size_t)n * NH * CS + cp;
        float a0 = 0.f, a1 = 0.f, c0 = 0.f, c1 = 0.f;
        #pragma unroll
        for (int h = 0; h < NH; ++h) {
            const float2 ev = *(const float2*)(ep + h * CS);
            a0 += dw0[h] * ev.x;  a1 += dw0[h] * ev.y;
            c0 += dw1[h] * ev.x;  c1 += dw1[h] * ev.y;
        }
        mA0[s] = a0; mA1[s] = a1; mB0[s] = c0; mB1[s] = c1;
    }

    // ---- scatter tile 0 into buffer 0 ----
    {
        float* d0p = s_xi[0][0 * 2 + rhalf];
        d0p[tgt0] = v[0].x; d0p[tgt1] = v[0].y; d0p[tgt2] = v[0].z; d0p[tgt3] = v[0].w;
        float* d1p = s_xi[0][1 * 2 + rhalf];
        d1p[tgt0] = v[1].x; d1p[tgt1] = v[1].y; d1p[tgt2] = v[1].z; d1p[tgt3] = v[1].w;
    }
    __syncthreads();

    // ---- main pipelined loop: ONE barrier per iteration ----
    for (int it = 0; it < NITER - 1; ++it) {
        const int cur = it & 1;

        // prefetch tile it+1
        v[0] = *(const float4*)(xp);
        v[1] = *(const float4*)(xp + 2 * F);
        xp += RPI * F;

        // compute RPI rows: per row 1 ds_read_b64 + 64 FMA + 30 DPP rotations
        #pragma unroll
        for (int r = 0; r < RPI; ++r) {
            const float2 xv = *(const float2*)(&s_xi[cur][r][xioff]);
            float x0 = xv.x, x1 = xv.y;
            float a0 = b0, a1 = b1;
            #pragma unroll
            for (int s = 0; s < 16; ++s) {
                a0 += mA0[s] * x0;
                a1 += mB0[s] * x0;
                a0 += mA1[s] * x1;
                a1 += mB1[s] * x1;
                if (s < 15) { x0 = ror1_f(x0); x1 = ror1_f(x1); }
            }
            *(float2*)(op + r * F) = make_float2(a0, a1);
        }
        op += RPI * F;

        // scatter prefetched tile into the other buffer
        {
            float* d0p = s_xi[cur ^ 1][0 * 2 + rhalf];
            d0p[tgt0] = v[0].x; d0p[tgt1] = v[0].y; d0p[tgt2] = v[0].z; d0p[tgt3] = v[0].w;
            float* d1p = s_xi[cur ^ 1][1 * 2 + rhalf];
            d1p[tgt0] = v[1].x; d1p[tgt1] = v[1].y; d1p[tgt2] = v[1].z; d1p[tgt3] = v[1].w;
        }
        __syncthreads();
    }

    // ---- peeled final tile: compute only ----
    {
        const int cur = (NITER - 1) & 1;
        #pragma unroll
        for (int r = 0; r < RPI; ++r) {
            const float2 xv = *(const float2*)(&s_xi[cur][r][xioff]);
            float x0 = xv.x, x1 = xv.y;
            float a0 = b0, a1 = b1;
            #pragma unroll
            for (int s = 0; s < 16; ++s) {
                a0 += mA0[s] * x0;
                a1 += mB0[s] * x0;
                a0 += mA1[s] * x1;
                a1 += mB1[s] * x1;
                if (s < 15) { x0 = ror1_f(x0); x1 = ror1_f(x1); }
            }
            *(float2*)(op + r * F) = make_float2(a0, a1);
        }
    }
}

extern "C" void kernel_launch(void* const* d_in, const int* in_sizes, int n_in,
                              void* d_out, int out_size, void* d_ws, size_t ws_size,
                              hipStream_t stream) {
    const float* x      = (const float*)d_in[0];
    const int*   clus   = (const int*)  d_in[1];
    const float* enc_w  = (const float*)d_in[2];
    const float* enc_b  = (const float*)d_in[3];
    const float* dec_w  = (const float*)d_in[4];
    const float* dec_b  = (const float*)d_in[5];
    float*       out    = (float*)d_out;

    ensemble_kernel<<<NBLOCKS, 256, 0, stream>>>(x, clus, enc_w, enc_b, dec_w, dec_b, out);
}